// Round 1
// baseline (5128.156 us; speedup 1.0000x reference)
//
#include <hip/hip_runtime.h>

// Problem constants (match reference)
#define Bdim 4
#define Ldim 512
#define Ddim 1024
#define Hdim 8
#define NLdim 2
#define NRdim 37
#define FFdim 4096
#define DHdim 128
#define ROWS (Bdim * Ldim)   // 2048 token rows

// ---------------------------------------------------------------------------
// LayerNorm: one block per row of 1024 floats, 256 threads (float4 each)
// ---------------------------------------------------------------------------
__global__ __launch_bounds__(256) void ln_kernel(
    const float* __restrict__ x, const float* __restrict__ g,
    const float* __restrict__ beta, float* __restrict__ out)
{
    int row = blockIdx.x;
    int t = threadIdx.x;
    const float4* xr = (const float4*)(x + (size_t)row * Ddim);
    float4 v = xr[t];
    float s  = v.x + v.y + v.z + v.w;
    float ss = v.x*v.x + v.y*v.y + v.z*v.z + v.w*v.w;
    #pragma unroll
    for (int off = 32; off; off >>= 1) {
        s  += __shfl_down(s, off);
        ss += __shfl_down(ss, off);
    }
    __shared__ float rs[4], rss[4], stat[2];
    int wave = t >> 6, lane = t & 63;
    if (lane == 0) { rs[wave] = s; rss[wave] = ss; }
    __syncthreads();
    if (t == 0) {
        float a = rs[0] + rs[1] + rs[2] + rs[3];
        float b = rss[0] + rss[1] + rss[2] + rss[3];
        float mean = a * (1.0f / Ddim);
        float var  = b * (1.0f / Ddim) - mean * mean;
        stat[0] = mean;
        stat[1] = rsqrtf(var + 1e-5f);
    }
    __syncthreads();
    float mean = stat[0], inv = stat[1];
    float4 gv = ((const float4*)g)[t];
    float4 bv = ((const float4*)beta)[t];
    float4 o;
    o.x = (v.x - mean) * inv * gv.x + bv.x;
    o.y = (v.y - mean) * inv * gv.y + bv.y;
    o.z = (v.z - mean) * inv * gv.z + bv.z;
    o.w = (v.w - mean) * inv * gv.w + bv.w;
    ((float4*)(out + (size_t)row * Ddim))[t] = o;
}

// ---------------------------------------------------------------------------
// fp32 GEMM: C[M,N] = op(A[M,K] @ W[K,N] + bias [+ res]), 128x128 tile, BK=8
// 256 threads, each computes 8x8 (split 4+4 rows / 4+4 cols to kill LDS
// bank conflicts: stride-4-float reads are 2-way -> free)
// ---------------------------------------------------------------------------
template<bool RELU, bool RES>
__global__ __launch_bounds__(256) void gemm_kernel(
    const float* __restrict__ A, const float* __restrict__ W,
    const float* __restrict__ bias, const float* __restrict__ res,
    float* __restrict__ C, int M, int N, int K)
{
    __shared__ __align__(16) float As[8][128];
    __shared__ __align__(16) float Bs[8][128];
    int t = threadIdx.x;
    int tx = t & 15, ty = t >> 4;
    int bm = blockIdx.y * 128, bn = blockIdx.x * 128;
    int lr = t >> 1, lc = (t & 1) * 4;        // A-tile load: row, k-col
    int brow = t >> 5, bcol = (t & 31) * 4;   // B-tile load: k-row, col
    const float* Aptr = A + (size_t)(bm + lr) * K + lc;
    const float* Bptr = W + (size_t)brow * N + bn + bcol;

    float acc[8][8];
    #pragma unroll
    for (int ii = 0; ii < 8; ++ii)
        #pragma unroll
        for (int jj = 0; jj < 8; ++jj)
            acc[ii][jj] = 0.f;

    for (int kt = 0; kt < K; kt += 8) {
        float4 av = *(const float4*)Aptr;
        float4 bv = *(const float4*)Bptr;
        __syncthreads();
        As[lc + 0][lr] = av.x;
        As[lc + 1][lr] = av.y;
        As[lc + 2][lr] = av.z;
        As[lc + 3][lr] = av.w;
        *(float4*)&Bs[brow][bcol] = bv;
        __syncthreads();
        Aptr += 8;
        Bptr += (size_t)8 * N;
        #pragma unroll
        for (int k = 0; k < 8; ++k) {
            float a[8], b[8];
            *(float4*)&a[0] = *(const float4*)&As[k][ty * 4];
            *(float4*)&a[4] = *(const float4*)&As[k][64 + ty * 4];
            *(float4*)&b[0] = *(const float4*)&Bs[k][tx * 4];
            *(float4*)&b[4] = *(const float4*)&Bs[k][64 + tx * 4];
            #pragma unroll
            for (int ii = 0; ii < 8; ++ii)
                #pragma unroll
                for (int jj = 0; jj < 8; ++jj)
                    acc[ii][jj] = fmaf(a[ii], b[jj], acc[ii][jj]);
        }
    }

    #pragma unroll
    for (int ii = 0; ii < 8; ++ii) {
        int r = bm + ty * 4 + (ii & 3) + ((ii >= 4) ? 64 : 0);
        size_t ro = (size_t)r * N;
        #pragma unroll
        for (int hh = 0; hh < 2; ++hh) {
            int c = bn + hh * 64 + tx * 4;
            float4 o = make_float4(acc[ii][hh*4+0], acc[ii][hh*4+1],
                                   acc[ii][hh*4+2], acc[ii][hh*4+3]);
            float4 bi = *(const float4*)&bias[c];
            o.x += bi.x; o.y += bi.y; o.z += bi.z; o.w += bi.w;
            if (RES) {
                float4 rr = *(const float4*)&res[ro + c];
                o.x += rr.x; o.y += rr.y; o.z += rr.z; o.w += rr.w;
            }
            if (RELU) {
                o.x = fmaxf(o.x, 0.f); o.y = fmaxf(o.y, 0.f);
                o.z = fmaxf(o.z, 0.f); o.w = fmaxf(o.w, 0.f);
            }
            *(float4*)&C[ro + c] = o;
        }
    }
}

// ---------------------------------------------------------------------------
// qr[b,i,h,r] = q[b,i,h*128:+128] . rel_k[r,:]  (one block per token row)
// rel_k staged transposed [d][r] (pad 40) so consecutive-r lanes are
// conflict-free; q-row reads broadcast.
// ---------------------------------------------------------------------------
__global__ __launch_bounds__(256) void qr_kernel(
    const float* __restrict__ q, const float* __restrict__ relk,
    float* __restrict__ qr)
{
    __shared__ __align__(16) float qrow[Ddim];
    __shared__ float rkT[DHdim][NRdim + 3];
    int bi = blockIdx.x, t = threadIdx.x;
    ((float4*)qrow)[t] = ((const float4*)(q + (size_t)bi * Ddim))[t];
    for (int idx = t; idx < NRdim * DHdim; idx += 256) {
        int r = idx >> 7, d = idx & 127;
        rkT[d][r] = relk[idx];
    }
    __syncthreads();
    for (int o = t; o < Hdim * NRdim; o += 256) {
        int h = o / NRdim, r = o - h * NRdim;
        const float* qp = qrow + h * DHdim;
        float acc = 0.f;
        #pragma unroll 4
        for (int d = 0; d < DHdim; ++d)
            acc = fmaf(qp[d], rkT[d][r], acc);
        qr[(size_t)bi * (Hdim * NRdim) + o] = acc;
    }
}

// ---------------------------------------------------------------------------
// Attention: one block (256 thr) per (b,h,i) query row.
//   scores[j] = (q.k_j + qr[rel(i,j)]) * scale     (j = 0..511)
//   softmax in LDS; aw[r] = sum_j p_j [rel==r] via LDS atomics
//   out[d] = (sum_j p_j v[j,d] + sum_r aw[r] rel_v[r,d]) / denom
// ---------------------------------------------------------------------------
__global__ __launch_bounds__(256) void attn_kernel(
    const float* __restrict__ q, const float* __restrict__ k,
    const float* __restrict__ v, const int* __restrict__ relations,
    const float* __restrict__ qr, const float* __restrict__ relv,
    float* __restrict__ oatt)
{
    __shared__ __align__(16) float s[Ldim];
    __shared__ unsigned short srel[Ldim];
    __shared__ __align__(16) float qrow[DHdim];
    __shared__ __align__(16) float relv_s[NRdim * DHdim];
    __shared__ float aw[NRdim];
    __shared__ float pv1[DHdim];
    __shared__ float red[4];

    int t = threadIdx.x;
    int blk = blockIdx.x;
    int i = blk & (Ldim - 1);
    int bh = blk >> 9;            // / 512
    int h = bh & (Hdim - 1);
    int b = bh >> 3;
    size_t rowq = (size_t)(b * Ldim + i) * Ddim + h * DHdim;

    if (t < 32) ((float4*)qrow)[t] = *((const float4*)(q + rowq) + t);
    if (t < NRdim) aw[t] = 0.f;
    for (int idx = t; idx < NRdim * DHdim; idx += 256) relv_s[idx] = relv[idx];
    const int* relrow = relations + ((size_t)b * Ldim + i) * Ldim;
    const float* qrp = qr + ((size_t)(b * Ldim + i) * Hdim + h) * NRdim;
    __syncthreads();

    const float scale = 0.08838834764831845f;  // 1/sqrt(128)
    #pragma unroll
    for (int rep = 0; rep < 2; ++rep) {
        int j = t + rep * 256;
        const float4* kp = (const float4*)(k + (size_t)(b * Ldim + j) * Ddim + h * DHdim);
        float acc = 0.f;
        #pragma unroll
        for (int d4 = 0; d4 < 32; ++d4) {
            float4 kv = kp[d4];
            float4 qv = ((const float4*)qrow)[d4];
            acc = fmaf(qv.x, kv.x, acc);
            acc = fmaf(qv.y, kv.y, acc);
            acc = fmaf(qv.z, kv.z, acc);
            acc = fmaf(qv.w, kv.w, acc);
        }
        int r = relrow[j];
        srel[j] = (unsigned short)r;
        s[j] = (acc + qrp[r]) * scale;
    }
    __syncthreads();

    // ---- softmax ----
    float m = fmaxf(s[t], s[t + 256]);
    #pragma unroll
    for (int off = 32; off; off >>= 1) m = fmaxf(m, __shfl_down(m, off));
    int wave = t >> 6, lane = t & 63;
    if (lane == 0) red[wave] = m;
    __syncthreads();
    m = fmaxf(fmaxf(red[0], red[1]), fmaxf(red[2], red[3]));
    float p0 = __expf(s[t] - m);
    float p1 = __expf(s[t + 256] - m);
    __syncthreads();              // red[] read-before-overwrite fence
    s[t] = p0;
    s[t + 256] = p1;
    float sum = p0 + p1;
    #pragma unroll
    for (int off = 32; off; off >>= 1) sum += __shfl_down(sum, off);
    if (lane == 0) red[wave] = sum;
    __syncthreads();
    float inv = 1.0f / (red[0] + red[1] + red[2] + red[3]);

    // relation buckets
    atomicAdd(&aw[srel[t]], p0);
    atomicAdd(&aw[srel[t + 256]], p1);
    __syncthreads();

    // ---- P @ V (half the j-range per thread group) + aw @ rel_v ----
    int d = t & 127, half = t >> 7;
    const float* vp = v + (size_t)(b * Ldim + half * 256) * Ddim + h * DHdim + d;
    float acc = 0.f;
    #pragma unroll 4
    for (int j = 0; j < 256; ++j)
        acc = fmaf(s[half * 256 + j], vp[(size_t)j * Ddim], acc);
    if (half) pv1[d] = acc;
    __syncthreads();
    if (t < 128) {
        float o = acc + pv1[t];
        float o2 = 0.f;
        #pragma unroll
        for (int r = 0; r < NRdim; ++r)
            o2 = fmaf(aw[r], relv_s[r * DHdim + t], o2);
        oatt[rowq + t] = (o + o2) * inv;
    }
}

// ---------------------------------------------------------------------------
extern "C" void kernel_launch(void* const* d_in, const int* in_sizes, int n_in,
                              void* d_out, int out_size, void* d_ws, size_t ws_size,
                              hipStream_t stream)
{
    const float* x     = (const float*)d_in[0];
    const int*   rel   = (const int*)  d_in[1];
    const float* Wq    = (const float*)d_in[2];
    const float* bq    = (const float*)d_in[3];
    const float* Wk    = (const float*)d_in[4];
    const float* bk    = (const float*)d_in[5];
    const float* Wv    = (const float*)d_in[6];
    const float* bv    = (const float*)d_in[7];
    const float* Wo    = (const float*)d_in[8];
    const float* bo    = (const float*)d_in[9];
    const float* rel_k = (const float*)d_in[10];
    const float* rel_v = (const float*)d_in[11];
    const float* W1    = (const float*)d_in[12];
    const float* b1    = (const float*)d_in[13];
    const float* W2    = (const float*)d_in[14];
    const float* b2    = (const float*)d_in[15];
    const float* ln1_g = (const float*)d_in[16];
    const float* ln1_b = (const float*)d_in[17];
    const float* ln2_g = (const float*)d_in[18];
    const float* ln2_b = (const float*)d_in[19];
    const float* lnf_g = (const float*)d_in[20];
    const float* lnf_b = (const float*)d_in[21];

    const size_t NTOK = (size_t)ROWS * Ddim;      // 2,097,152 floats
    float* xbuf = (float*)d_ws;
    float* hbuf = xbuf + NTOK;
    float* qb   = hbuf + NTOK;
    float* kb   = qb   + NTOK;
    float* vbuf = kb   + NTOK;
    float* ob   = vbuf + NTOK;
    float* qrb  = ob   + NTOK;                    // ROWS*H*NR floats
    float* ffb  = qb;                             // aliases q/k/v/o (= ROWS*FF)

    hipMemcpyAsync(xbuf, x, sizeof(float) * NTOK, hipMemcpyDeviceToDevice, stream);

    dim3 blk256(256);
    dim3 g_d(Ddim / 128, ROWS / 128);     // (8,16)
    dim3 g_ff(FFdim / 128, ROWS / 128);   // (32,16)

    for (int l = 0; l < NLdim; ++l) {
        const float* Wq_l = Wq + (size_t)l * Ddim * Ddim;
        const float* Wk_l = Wk + (size_t)l * Ddim * Ddim;
        const float* Wv_l = Wv + (size_t)l * Ddim * Ddim;
        const float* Wo_l = Wo + (size_t)l * Ddim * Ddim;
        const float* W1_l = W1 + (size_t)l * Ddim * FFdim;
        const float* W2_l = W2 + (size_t)l * FFdim * Ddim;
        const float* rk_l = rel_k + (size_t)l * NRdim * DHdim;
        const float* rv_l = rel_v + (size_t)l * NRdim * DHdim;

        ln_kernel<<<ROWS, blk256, 0, stream>>>(xbuf, ln1_g + l * Ddim, ln1_b + l * Ddim, hbuf);
        gemm_kernel<false, false><<<g_d, blk256, 0, stream>>>(hbuf, Wq_l, bq + l * Ddim, nullptr, qb,   ROWS, Ddim, Ddim);
        gemm_kernel<false, false><<<g_d, blk256, 0, stream>>>(hbuf, Wk_l, bk + l * Ddim, nullptr, kb,   ROWS, Ddim, Ddim);
        gemm_kernel<false, false><<<g_d, blk256, 0, stream>>>(hbuf, Wv_l, bv + l * Ddim, nullptr, vbuf, ROWS, Ddim, Ddim);
        qr_kernel<<<ROWS, blk256, 0, stream>>>(qb, rk_l, qrb);
        attn_kernel<<<Bdim * Hdim * Ldim, blk256, 0, stream>>>(qb, kb, vbuf, rel, qrb, rv_l, ob);
        gemm_kernel<false, true><<<g_d, blk256, 0, stream>>>(ob, Wo_l, bo + l * Ddim, xbuf, xbuf, ROWS, Ddim, Ddim);
        ln_kernel<<<ROWS, blk256, 0, stream>>>(xbuf, ln2_g + l * Ddim, ln2_b + l * Ddim, hbuf);
        gemm_kernel<true, false><<<g_ff, blk256, 0, stream>>>(hbuf, W1_l, b1 + l * FFdim, nullptr, ffb, ROWS, FFdim, Ddim);
        gemm_kernel<false, true><<<g_d, blk256, 0, stream>>>(ffb, W2_l, b2 + l * Ddim, xbuf, xbuf, ROWS, Ddim, FFdim);
    }
    ln_kernel<<<ROWS, blk256, 0, stream>>>(xbuf, lnf_g, lnf_b, (float*)d_out);
}

// Round 6
// 1081.244 us; speedup vs baseline: 4.7428x; 4.7428x over previous
//
#include <hip/hip_runtime.h>

#define Bdim 4
#define Ldim 512
#define Ddim 1024
#define Hdim 8
#define NLdim 2
#define NRdim 37
#define FFdim 4096
#define DHdim 128
#define ROWS 2048

using bf16x8 = __attribute__((ext_vector_type(8))) short;
using s16x4  = __attribute__((ext_vector_type(4))) short;
using s16x8  = __attribute__((ext_vector_type(8))) short;
using f32x4  = __attribute__((ext_vector_type(4))) float;

// RNE split: f ~= hi + lo (both bf16), residual ~2^-17 relative.
// Returned by value (ext_vector elements can't bind to short&).
struct HL { short h, l; };
__device__ __forceinline__ HL splitf(float f) {
    HL r;
    unsigned u = __float_as_uint(f);
    unsigned rh = (u + 0x7FFFu + ((u >> 16) & 1u)) >> 16;
    r.h = (short)rh;
    float res = f - __uint_as_float(rh << 16);
    unsigned v = __float_as_uint(res);
    r.l = (short)((v + 0x7FFFu + ((v >> 16) & 1u)) >> 16);
    return r;
}

// split-swizzled activation layout: row-major, row length KK, groups of 8
// elements permuted within each 64-elem k-tile by XOR(row&7)
__device__ __forceinline__ size_t ssa_off(int row, int k, int KK) {
    return (size_t)row * KK + (k & ~63) + (((((k >> 3) & 7) ^ (row & 7))) << 3) + (k & 7);
}

__device__ __forceinline__ void gload16(const void* g, void* l) {
    __builtin_amdgcn_global_load_lds(
        (const __attribute__((address_space(1))) void*)g,
        (__attribute__((address_space(3))) void*)l, 16, 0, 0);
}

// ---------------------------------------------------------------------------
// LayerNorm: one block per row; SPLIT emits swizzled bf16 hi/lo, else fp32
// ---------------------------------------------------------------------------
template<bool SPLIT>
__global__ __launch_bounds__(256) void ln_kernel(
    const float* __restrict__ x, const float* __restrict__ g,
    const float* __restrict__ beta, float* __restrict__ outf,
    short* __restrict__ oh, short* __restrict__ ol)
{
    int row = blockIdx.x;
    int t = threadIdx.x;
    const float4* xr = (const float4*)(x + (size_t)row * Ddim);
    float4 v = xr[t];
    float s  = v.x + v.y + v.z + v.w;
    float ss = v.x*v.x + v.y*v.y + v.z*v.z + v.w*v.w;
    #pragma unroll
    for (int off = 32; off; off >>= 1) {
        s  += __shfl_down(s, off);
        ss += __shfl_down(ss, off);
    }
    __shared__ float rs[4], rss[4], stat[2];
    int wave = t >> 6, lane = t & 63;
    if (lane == 0) { rs[wave] = s; rss[wave] = ss; }
    __syncthreads();
    if (t == 0) {
        float a = rs[0] + rs[1] + rs[2] + rs[3];
        float b = rss[0] + rss[1] + rss[2] + rss[3];
        float mean = a * (1.0f / Ddim);
        float var  = b * (1.0f / Ddim) - mean * mean;
        stat[0] = mean;
        stat[1] = rsqrtf(var + 1e-5f);
    }
    __syncthreads();
    float mean = stat[0], inv = stat[1];
    float4 gv = ((const float4*)g)[t];
    float4 bv = ((const float4*)beta)[t];
    float4 o;
    o.x = (v.x - mean) * inv * gv.x + bv.x;
    o.y = (v.y - mean) * inv * gv.y + bv.y;
    o.z = (v.z - mean) * inv * gv.z + bv.z;
    o.w = (v.w - mean) * inv * gv.w + bv.w;
    if (SPLIT) {
        int d = t * 4;
        size_t off = ssa_off(row, d, Ddim);
        HL a0 = splitf(o.x), a1 = splitf(o.y), a2 = splitf(o.z), a3 = splitf(o.w);
        s16x4 hv, lv;
        hv[0] = a0.h; hv[1] = a1.h; hv[2] = a2.h; hv[3] = a3.h;
        lv[0] = a0.l; lv[1] = a1.l; lv[2] = a2.l; lv[3] = a3.l;
        *(s16x4*)&oh[off] = hv;
        *(s16x4*)&ol[off] = lv;
    } else {
        ((float4*)(outf + (size_t)row * Ddim))[t] = o;
    }
}

// ---------------------------------------------------------------------------
// Weight prepass: W[K,N] fp32 -> transposed split slabs [kt][n][g'][8] bf16
// ---------------------------------------------------------------------------
__global__ __launch_bounds__(256) void prep_w(
    const float* __restrict__ W, short* __restrict__ oh, short* __restrict__ ol,
    int N, int logN)
{
    int gi = blockIdx.x * 256 + threadIdx.x;   // < K*N/8
    int n = gi & (N - 1);
    int rest = gi >> logN;                     // kt*8 + g
    int g = rest & 7, kt = rest >> 3;
    const float* src = W + ((size_t)(kt * 64 + g * 8)) * N + n;
    s16x8 h8, l8;
    #pragma unroll
    for (int j = 0; j < 8; ++j) {
        HL a = splitf(src[(size_t)j * N]);
        h8[j] = a.h; l8[j] = a.l;
    }
    size_t off = ((size_t)kt * N + n) * 64 + (((g ^ (n & 7))) << 3);
    *(s16x8*)&oh[off] = h8;
    *(s16x8*)&ol[off] = l8;
}

// ---------------------------------------------------------------------------
// bf16x3 MFMA GEMM: C[M=2048,N] = A[M,K] @ W[K,N]; A,W pre-split bf16 hi/lo.
// BM=128 BN=64 BK=64, 256 thr (4 waves, 64x32 wave-tile), 16x16x32 MFMA.
// grid.z selects pointer set (QKV batching).
// ---------------------------------------------------------------------------
struct G3 {
    const short* Wh[3]; const short* Wl[3];
    const float* bias[3];
    float* outf[3];
    short* oh[3]; short* ol[3];
};

template<bool RES, bool RELU, bool SPLIT>
__global__ __launch_bounds__(256) void gemm3(
    const short* __restrict__ Ahi, const short* __restrict__ Alo,
    const float* __restrict__ res, G3 gp, int N, int K)
{
    __shared__ __align__(16) short As_h[128 * 64];
    __shared__ __align__(16) short As_l[128 * 64];
    __shared__ __align__(16) short Ws_h[64 * 64];
    __shared__ __align__(16) short Ws_l[64 * 64];

    int z = blockIdx.z;
    const short* Wh = gp.Wh[z];
    const short* Wl = gp.Wl[z];
    const float* bias = gp.bias[z];

    int t = threadIdx.x, wid = t >> 6, lane = t & 63;
    int bm = blockIdx.y * 128, bn = blockIdx.x * 64;
    int wr = wid >> 1, wc = wid & 1;

    f32x4 acc[4][2];
    #pragma unroll
    for (int m = 0; m < 4; ++m)
        #pragma unroll
        for (int n = 0; n < 2; ++n)
            acc[m][n] = (f32x4)(0.f);

    int nkt = K >> 6;
    int l8r = lane >> 3, l8c = lane & 7;   // 8 rows x 8 chunks per gload

    for (int kt = 0; kt < nkt; ++kt) {
        size_t kof = (size_t)kt * 64 + l8c * 8;
        #pragma unroll
        for (int qq = 0; qq < 4; ++qq) {
            int rb = wid * 32 + qq * 8;
            gload16(Ahi + (size_t)(bm + rb + l8r) * K + kof, &As_h[rb * 64]);
            gload16(Alo + (size_t)(bm + rb + l8r) * K + kof, &As_l[rb * 64]);
        }
        size_t wbase = (size_t)kt * N * 64;
        #pragma unroll
        for (int qq = 0; qq < 2; ++qq) {
            int nb = wid * 16 + qq * 8;
            gload16(Wh + wbase + (size_t)(bn + nb + l8r) * 64 + l8c * 8, &Ws_h[nb * 64]);
            gload16(Wl + wbase + (size_t)(bn + nb + l8r) * 64 + l8c * 8, &Ws_l[nb * 64]);
        }
        __syncthreads();
        #pragma unroll
        for (int ks = 0; ks < 2; ++ks) {
            int kg = ks * 4 + (lane >> 4);
            int sw = (kg ^ (lane & 7)) << 3;
            bf16x8 ah[4], al[4], bh[2], bl[2];
            #pragma unroll
            for (int m = 0; m < 4; ++m) {
                int off = (wr * 64 + m * 16 + (lane & 15)) * 64 + sw;
                ah[m] = *(const bf16x8*)&As_h[off];
                al[m] = *(const bf16x8*)&As_l[off];
            }
            #pragma unroll
            for (int n = 0; n < 2; ++n) {
                int off = (wc * 32 + n * 16 + (lane & 15)) * 64 + sw;
                bh[n] = *(const bf16x8*)&Ws_h[off];
                bl[n] = *(const bf16x8*)&Ws_l[off];
            }
            #pragma unroll
            for (int m = 0; m < 4; ++m)
                #pragma unroll
                for (int n = 0; n < 2; ++n) {
                    acc[m][n] = __builtin_amdgcn_mfma_f32_16x16x32_bf16(ah[m], bh[n], acc[m][n], 0, 0, 0);
                    acc[m][n] = __builtin_amdgcn_mfma_f32_16x16x32_bf16(ah[m], bl[n], acc[m][n], 0, 0, 0);
                    acc[m][n] = __builtin_amdgcn_mfma_f32_16x16x32_bf16(al[m], bh[n], acc[m][n], 0, 0, 0);
                }
        }
        __syncthreads();
    }

    // epilogue: C/D frag: col = lane&15, row = (lane>>4)*4 + j
    int r0 = (lane >> 4) << 2, cl = lane & 15;
    #pragma unroll
    for (int m = 0; m < 4; ++m) {
        #pragma unroll
        for (int n = 0; n < 2; ++n) {
            int col = bn + wc * 32 + n * 16 + cl;
            float bia = bias[col];
            #pragma unroll
            for (int j = 0; j < 4; ++j) {
                int row = bm + wr * 64 + m * 16 + r0 + j;
                float val = acc[m][n][j] + bia;
                if (RES) val += res[(size_t)row * N + col];
                if (RELU) val = fmaxf(val, 0.f);
                if (SPLIT) {
                    HL a = splitf(val);
                    size_t o = ssa_off(row, col, N);
                    gp.oh[z][o] = a.h;
                    gp.ol[z][o] = a.l;
                } else {
                    gp.outf[z][(size_t)row * N + col] = val;
                }
            }
        }
    }
}

// ---------------------------------------------------------------------------
// qr[b,i,h,r] = q[b,i,h*128:+128] . rel_k[r,:]  (one block per token row)
// ---------------------------------------------------------------------------
__global__ __launch_bounds__(256) void qr_kernel(
    const float* __restrict__ q, const float* __restrict__ relk,
    float* __restrict__ qr)
{
    __shared__ __align__(16) float qrow[Ddim];
    __shared__ float rkT[DHdim][NRdim + 3];
    int bi = blockIdx.x, t = threadIdx.x;
    ((float4*)qrow)[t] = ((const float4*)(q + (size_t)bi * Ddim))[t];
    for (int idx = t; idx < NRdim * DHdim; idx += 256) {
        int r = idx >> 7, d = idx & 127;
        rkT[d][r] = relk[idx];
    }
    __syncthreads();
    for (int o = t; o < Hdim * NRdim; o += 256) {
        int h = o / NRdim, r = o - h * NRdim;
        const float* qp = qrow + h * DHdim;
        float acc = 0.f;
        #pragma unroll 4
        for (int d = 0; d < DHdim; ++d)
            acc = fmaf(qp[d], rkT[d][r], acc);
        qr[(size_t)bi * (Hdim * NRdim) + o] = acc;
    }
}

// ---------------------------------------------------------------------------
// Attention v2: block per (b,h, 32-query-row tile); online softmax over
// 16 j-tiles of 32; fp32 vector math in LDS; emits split-swizzled bf16 o.
// thread t: row r = t>>3 (0..31), octet lane q8 = t&7.
// ---------------------------------------------------------------------------
__global__ __launch_bounds__(256) void attn_kernel(
    const float* __restrict__ q, const float* __restrict__ k,
    const float* __restrict__ v, const int* __restrict__ relations,
    const float* __restrict__ qr, const float* __restrict__ relv,
    short* __restrict__ o_hi, short* __restrict__ o_lo)
{
    __shared__ __align__(16) float Qs[32][132];
    __shared__ __align__(16) float Ks[32][132];
    __shared__ __align__(16) float Vs[32][132];
    __shared__ float Ps[32][36];
    __shared__ float aw[32][40];

    int t = threadIdx.x;
    int blk = blockIdx.x;              // 512 = 16 itiles x (b*8+h)
    int it = blk & 15, bh = blk >> 4;
    int h = bh & 7, b = bh >> 3;
    int i0 = it * 32;
    int r = t >> 3, q8 = t & 7;
    int row_g = b * Ldim + i0 + r;

    // stage Q tile
    const float* qrow = q + (size_t)row_g * Ddim + h * DHdim;
    #pragma unroll
    for (int c = 0; c < 4; ++c)
        *(float4*)&Qs[r][q8 * 16 + c * 4] = *(const float4*)&qrow[q8 * 16 + c * 4];
    for (int idx = t; idx < 32 * 40; idx += 256) ((float*)aw)[idx] = 0.f;

    const int*   relp = relations + (size_t)row_g * Ldim;
    const float* qrp  = qr + (size_t)row_g * (Hdim * NRdim) + h * NRdim;

    float4 oc0 = make_float4(0,0,0,0), oc1 = oc0, oc2 = oc0, oc3 = oc0;
    float mrun = -1e30f, lsum = 0.f;
    const float scale = 0.08838834764831845f;

    for (int jt = 0; jt < 16; ++jt) {
        int j0 = jt * 32;
        __syncthreads();   // prior tile's Ks/Vs consumers done
        const float* krow = k + (size_t)(b * Ldim + j0 + r) * Ddim + h * DHdim;
        const float* vrow = v + (size_t)(b * Ldim + j0 + r) * Ddim + h * DHdim;
        #pragma unroll
        for (int c = 0; c < 4; ++c) {
            *(float4*)&Ks[r][q8 * 16 + c * 4] = *(const float4*)&krow[q8 * 16 + c * 4];
            *(float4*)&Vs[r][q8 * 16 + c * 4] = *(const float4*)&vrow[q8 * 16 + c * 4];
        }
        __syncthreads();

        // QK: this thread's 4 columns j = q8 + 8*jl
        float s0 = 0.f, s1 = 0.f, s2 = 0.f, s3 = 0.f;
        #pragma unroll 8
        for (int dq = 0; dq < 32; ++dq) {
            float4 qv = *(const float4*)&Qs[r][dq * 4];
            float4 k0 = *(const float4*)&Ks[q8     ][dq * 4];
            float4 k1 = *(const float4*)&Ks[q8 +  8][dq * 4];
            float4 k2 = *(const float4*)&Ks[q8 + 16][dq * 4];
            float4 k3 = *(const float4*)&Ks[q8 + 24][dq * 4];
            s0 = fmaf(qv.x, k0.x, s0); s0 = fmaf(qv.y, k0.y, s0); s0 = fmaf(qv.z, k0.z, s0); s0 = fmaf(qv.w, k0.w, s0);
            s1 = fmaf(qv.x, k1.x, s1); s1 = fmaf(qv.y, k1.y, s1); s1 = fmaf(qv.z, k1.z, s1); s1 = fmaf(qv.w, k1.w, s1);
            s2 = fmaf(qv.x, k2.x, s2); s2 = fmaf(qv.y, k2.y, s2); s2 = fmaf(qv.z, k2.z, s2); s2 = fmaf(qv.w, k2.w, s2);
            s3 = fmaf(qv.x, k3.x, s3); s3 = fmaf(qv.y, k3.y, s3); s3 = fmaf(qv.z, k3.z, s3); s3 = fmaf(qv.w, k3.w, s3);
        }
        int rel0 = relp[j0 + q8];
        int rel1 = relp[j0 + q8 + 8];
        int rel2 = relp[j0 + q8 + 16];
        int rel3 = relp[j0 + q8 + 24];
        s0 = (s0 + qrp[rel0]) * scale;
        s1 = (s1 + qrp[rel1]) * scale;
        s2 = (s2 + qrp[rel2]) * scale;
        s3 = (s3 + qrp[rel3]) * scale;

        // row max over octet
        float mt = fmaxf(fmaxf(s0, s1), fmaxf(s2, s3));
        mt = fmaxf(mt, __shfl_xor(mt, 1));
        mt = fmaxf(mt, __shfl_xor(mt, 2));
        mt = fmaxf(mt, __shfl_xor(mt, 4));
        float mnew = fmaxf(mrun, mt);
        float corr = __expf(mrun - mnew);
        mrun = mnew;
        float p0 = __expf(s0 - mnew);
        float p1 = __expf(s1 - mnew);
        float p2 = __expf(s2 - mnew);
        float p3 = __expf(s3 - mnew);
        lsum = lsum * corr + (p0 + p1 + p2 + p3);
        oc0.x *= corr; oc0.y *= corr; oc0.z *= corr; oc0.w *= corr;
        oc1.x *= corr; oc1.y *= corr; oc1.z *= corr; oc1.w *= corr;
        oc2.x *= corr; oc2.y *= corr; oc2.z *= corr; oc2.w *= corr;
        oc3.x *= corr; oc3.y *= corr; oc3.z *= corr; oc3.w *= corr;
        // rescale relation buckets (disjoint slices within row octet, in-wave)
        for (int ri = q8; ri < NRdim; ri += 8) aw[r][ri] *= corr;
        atomicAdd(&aw[r][rel0], p0);
        atomicAdd(&aw[r][rel1], p1);
        atomicAdd(&aw[r][rel2], p2);
        atomicAdd(&aw[r][rel3], p3);
        Ps[r][q8]      = p0;
        Ps[r][q8 + 8]  = p1;
        Ps[r][q8 + 16] = p2;
        Ps[r][q8 + 24] = p3;

        // PV (Ps written/read within the same row octet -> same wave, no barrier)
        #pragma unroll 4
        for (int j = 0; j < 32; ++j) {
            float p = Ps[r][j];
            float4 v0 = *(const float4*)&Vs[j][(q8     ) * 4];
            float4 v1 = *(const float4*)&Vs[j][(q8 +  8) * 4];
            float4 v2 = *(const float4*)&Vs[j][(q8 + 16) * 4];
            float4 v3 = *(const float4*)&Vs[j][(q8 + 24) * 4];
            oc0.x = fmaf(p, v0.x, oc0.x); oc0.y = fmaf(p, v0.y, oc0.y); oc0.z = fmaf(p, v0.z, oc0.z); oc0.w = fmaf(p, v0.w, oc0.w);
            oc1.x = fmaf(p, v1.x, oc1.x); oc1.y = fmaf(p, v1.y, oc1.y); oc1.z = fmaf(p, v1.z, oc1.z); oc1.w = fmaf(p, v1.w, oc1.w);
            oc2.x = fmaf(p, v2.x, oc2.x); oc2.y = fmaf(p, v2.y, oc2.y); oc2.z = fmaf(p, v2.z, oc2.z); oc2.w = fmaf(p, v2.w, oc2.w);
            oc3.x = fmaf(p, v3.x, oc3.x); oc3.y = fmaf(p, v3.y, oc3.y); oc3.z = fmaf(p, v3.z, oc3.z); oc3.w = fmaf(p, v3.w, oc3.w);
        }
    }

    lsum += __shfl_xor(lsum, 1);
    lsum += __shfl_xor(lsum, 2);
    lsum += __shfl_xor(lsum, 4);
    float inv = 1.0f / lsum;

    // o2 = aw @ rel_v  (relv from global; L2-resident 19KB)
    float4 o20 = make_float4(0,0,0,0), o21 = o20, o22 = o20, o23 = o20;
    for (int rp = 0; rp < NRdim; ++rp) {
        float w = aw[r][rp];
        const float4* rv = (const float4*)(relv + (size_t)rp * DHdim);
        float4 a0 = rv[q8], a1 = rv[q8 + 8], a2 = rv[q8 + 16], a3 = rv[q8 + 24];
        o20.x = fmaf(w, a0.x, o20.x); o20.y = fmaf(w, a0.y, o20.y); o20.z = fmaf(w, a0.z, o20.z); o20.w = fmaf(w, a0.w, o20.w);
        o21.x = fmaf(w, a1.x, o21.x); o21.y = fmaf(w, a1.y, o21.y); o21.z = fmaf(w, a1.z, o21.z); o21.w = fmaf(w, a1.w, o21.w);
        o22.x = fmaf(w, a2.x, o22.x); o22.y = fmaf(w, a2.y, o22.y); o22.z = fmaf(w, a2.z, o22.z); o22.w = fmaf(w, a2.w, o22.w);
        o23.x = fmaf(w, a3.x, o23.x); o23.y = fmaf(w, a3.y, o23.y); o23.z = fmaf(w, a3.z, o23.z); o23.w = fmaf(w, a3.w, o23.w);
    }

    float4 vals[4];
    vals[0].x = (oc0.x + o20.x) * inv; vals[0].y = (oc0.y + o20.y) * inv; vals[0].z = (oc0.z + o20.z) * inv; vals[0].w = (oc0.w + o20.w) * inv;
    vals[1].x = (oc1.x + o21.x) * inv; vals[1].y = (oc1.y + o21.y) * inv; vals[1].z = (oc1.z + o21.z) * inv; vals[1].w = (oc1.w + o21.w) * inv;
    vals[2].x = (oc2.x + o22.x) * inv; vals[2].y = (oc2.y + o22.y) * inv; vals[2].z = (oc2.z + o22.z) * inv; vals[2].w = (oc2.w + o22.w) * inv;
    vals[3].x = (oc3.x + o23.x) * inv; vals[3].y = (oc3.y + o23.y) * inv; vals[3].z = (oc3.z + o23.z) * inv; vals[3].w = (oc3.w + o23.w) * inv;
    #pragma unroll
    for (int c = 0; c < 4; ++c) {
        int d = (q8 + 8 * c) * 4;
        int kk = h * DHdim + d;
        size_t off = ssa_off(row_g, kk, Ddim);
        HL a0 = splitf(vals[c].x), a1 = splitf(vals[c].y),
           a2 = splitf(vals[c].z), a3 = splitf(vals[c].w);
        s16x4 hv, lv;
        hv[0] = a0.h; hv[1] = a1.h; hv[2] = a2.h; hv[3] = a3.h;
        lv[0] = a0.l; lv[1] = a1.l; lv[2] = a2.l; lv[3] = a3.l;
        *(s16x4*)&o_hi[off] = hv;
        *(s16x4*)&o_lo[off] = lv;
    }
}

// ---------------------------------------------------------------------------
extern "C" void kernel_launch(void* const* d_in, const int* in_sizes, int n_in,
                              void* d_out, int out_size, void* d_ws, size_t ws_size,
                              hipStream_t stream)
{
    const float* x     = (const float*)d_in[0];
    const int*   rel   = (const int*)  d_in[1];
    const float* Wq    = (const float*)d_in[2];
    const float* bq    = (const float*)d_in[3];
    const float* Wk    = (const float*)d_in[4];
    const float* bk    = (const float*)d_in[5];
    const float* Wv    = (const float*)d_in[6];
    const float* bv    = (const float*)d_in[7];
    const float* Wo    = (const float*)d_in[8];
    const float* bo    = (const float*)d_in[9];
    const float* rel_k = (const float*)d_in[10];
    const float* rel_v = (const float*)d_in[11];
    const float* W1    = (const float*)d_in[12];
    const float* b1    = (const float*)d_in[13];
    const float* W2    = (const float*)d_in[14];
    const float* b2    = (const float*)d_in[15];
    const float* ln1_g = (const float*)d_in[16];
    const float* ln1_b = (const float*)d_in[17];
    const float* ln2_g = (const float*)d_in[18];
    const float* ln2_b = (const float*)d_in[19];
    const float* lnf_g = (const float*)d_in[20];
    const float* lnf_b = (const float*)d_in[21];

    const size_t MB = 1u << 20;
    char* w = (char*)d_ws;
    float* xbuf = (float*)w;                       // [0,8MB)
    short* h_hi = (short*)(w + 8 * MB);            // [8,12)
    short* h_lo = (short*)(w + 12 * MB);           // [12,16)
    char*  regC = w + 16 * MB;                     // [16,48) phase union
    float* qb   = (float*)regC;                    // [16,24)
    float* kb   = (float*)(regC + 8 * MB);         // [24,32)
    float* vb   = (float*)(regC + 16 * MB);        // [32,40)
    float* qrb  = (float*)(regC + 24 * MB);        // [40,42.4)
    short* ffh  = (short*)regC;                    // [16,32)  (aliases q/k)
    short* ffl  = (short*)(regC + 16 * MB);        // [32,48)  (aliases v/qr)
    short* o_hi = (short*)(w + 48 * MB);           // [48,52)
    short* o_lo = (short*)(w + 52 * MB);           // [52,56)
    short* wbh  = (short*)(w + 56 * MB);           // [56,64)  4M shorts
    short* wbl  = (short*)(w + 64 * MB);           // [64,72)

    (void)hipMemcpyAsync(xbuf, x, sizeof(float) * (size_t)ROWS * Ddim,
                         hipMemcpyDeviceToDevice, stream);

    dim3 blk(256);
    const size_t MSH = 1048576;   // 1M shorts: one D x D weight

    for (int l = 0; l < NLdim; ++l) {
        const float* Wq_l = Wq + (size_t)l * Ddim * Ddim;
        const float* Wk_l = Wk + (size_t)l * Ddim * Ddim;
        const float* Wv_l = Wv + (size_t)l * Ddim * Ddim;
        const float* Wo_l = Wo + (size_t)l * Ddim * Ddim;
        const float* W1_l = W1 + (size_t)l * Ddim * FFdim;
        const float* W2_l = W2 + (size_t)l * FFdim * Ddim;
        const float* rk_l = rel_k + (size_t)l * NRdim * DHdim;
        const float* rv_l = rel_v + (size_t)l * NRdim * DHdim;

        // --- attention sublayer ---
        ln_kernel<true><<<ROWS, blk, 0, stream>>>(xbuf, ln1_g + l * Ddim, ln1_b + l * Ddim,
                                                  nullptr, h_hi, h_lo);
        prep_w<<<512, blk, 0, stream>>>(Wq_l, wbh, wbl, Ddim, 10);
        prep_w<<<512, blk, 0, stream>>>(Wk_l, wbh + MSH, wbl + MSH, Ddim, 10);
        prep_w<<<512, blk, 0, stream>>>(Wv_l, wbh + 2 * MSH, wbl + 2 * MSH, Ddim, 10);
        {
            G3 g{};
            g.Wh[0] = wbh;           g.Wl[0] = wbl;
            g.Wh[1] = wbh + MSH;     g.Wl[1] = wbl + MSH;
            g.Wh[2] = wbh + 2 * MSH; g.Wl[2] = wbl + 2 * MSH;
            g.bias[0] = bq + l * Ddim; g.bias[1] = bk + l * Ddim; g.bias[2] = bv + l * Ddim;
            g.outf[0] = qb; g.outf[1] = kb; g.outf[2] = vb;
            gemm3<false, false, false><<<dim3(16, 16, 3), blk, 0, stream>>>(
                h_hi, h_lo, nullptr, g, Ddim, Ddim);
        }
        qr_kernel<<<ROWS, blk, 0, stream>>>(qb, rk_l, qrb);
        attn_kernel<<<512, blk, 0, stream>>>(qb, kb, vb, rel, qrb, rv_l, o_hi, o_lo);
        prep_w<<<512, blk, 0, stream>>>(Wo_l, wbh, wbl, Ddim, 10);
        {
            G3 g{};
            g.Wh[0] = wbh; g.Wl[0] = wbl;
            g.bias[0] = bo + l * Ddim;
            g.outf[0] = xbuf;
            gemm3<true, false, false><<<dim3(16, 16, 1), blk, 0, stream>>>(
                o_hi, o_lo, xbuf, g, Ddim, Ddim);
        }
        // --- FFN sublayer ---
        ln_kernel<true><<<ROWS, blk, 0, stream>>>(xbuf, ln2_g + l * Ddim, ln2_b + l * Ddim,
                                                  nullptr, h_hi, h_lo);
        prep_w<<<2048, blk, 0, stream>>>(W1_l, wbh, wbl, FFdim, 12);
        {
            G3 g{};
            g.Wh[0] = wbh; g.Wl[0] = wbl;
            g.bias[0] = b1 + l * FFdim;
            g.oh[0] = ffh; g.ol[0] = ffl;
            gemm3<false, true, true><<<dim3(64, 16, 1), blk, 0, stream>>>(
                h_hi, h_lo, nullptr, g, FFdim, Ddim);
        }
        prep_w<<<2048, blk, 0, stream>>>(W2_l, wbh, wbl, Ddim, 10);
        {
            G3 g{};
            g.Wh[0] = wbh; g.Wl[0] = wbl;
            g.bias[0] = b2 + l * Ddim;
            g.outf[0] = xbuf;
            gemm3<true, false, false><<<dim3(16, 16, 1), blk, 0, stream>>>(
                ffh, ffl, xbuf, g, Ddim, FFdim);
        }
    }
    ln_kernel<false><<<ROWS, blk, 0, stream>>>(xbuf, lnf_g, lnf_b, (float*)d_out,
                                               nullptr, nullptr);
}

// Round 7
// 938.558 us; speedup vs baseline: 5.4639x; 1.1520x over previous
//
#include <hip/hip_runtime.h>

#define Bdim 4
#define Ldim 512
#define Ddim 1024
#define Hdim 8
#define NLdim 2
#define NRdim 37
#define FFdim 4096
#define DHdim 128
#define ROWS 2048

using bf16x8 = __attribute__((ext_vector_type(8))) short;
using s16x4  = __attribute__((ext_vector_type(4))) short;
using s16x8  = __attribute__((ext_vector_type(8))) short;
using f32x4  = __attribute__((ext_vector_type(4))) float;
using u32 = unsigned int;

// RNE split: f ~= hi + lo (both bf16)
struct HL { short h, l; };
__device__ __forceinline__ HL splitf(float f) {
    HL r;
    unsigned u = __float_as_uint(f);
    unsigned rh = (u + 0x7FFFu + ((u >> 16) & 1u)) >> 16;
    r.h = (short)rh;
    float res = f - __uint_as_float(rh << 16);
    unsigned v = __float_as_uint(res);
    r.l = (short)((v + 0x7FFFu + ((v >> 16) & 1u)) >> 16);
    return r;
}
__device__ __forceinline__ float b2f(short s) {
    return __uint_as_float(((unsigned)(unsigned short)s) << 16);
}

// split-swizzled activation layout: row-major, groups of 8 elements permuted
// within each 64-elem k-tile by XOR(row&7)
__device__ __forceinline__ size_t ssa_off(int row, int k, int KK) {
    return (size_t)row * KK + (k & ~63) + (((((k >> 3) & 7) ^ (row & 7))) << 3) + (k & 7);
}

__device__ __forceinline__ void gload16(const void* g, void* l) {
    __builtin_amdgcn_global_load_lds(
        (const __attribute__((address_space(1))) void*)g,
        (__attribute__((address_space(3))) void*)l, 16, 0, 0);
}

// ---------------------------------------------------------------------------
// LayerNorm (unchanged from R6)
// ---------------------------------------------------------------------------
template<bool SPLIT>
__global__ __launch_bounds__(256) void ln_kernel(
    const float* __restrict__ x, const float* __restrict__ g,
    const float* __restrict__ beta, float* __restrict__ outf,
    short* __restrict__ oh, short* __restrict__ ol)
{
    int row = blockIdx.x;
    int t = threadIdx.x;
    const float4* xr = (const float4*)(x + (size_t)row * Ddim);
    float4 v = xr[t];
    float s  = v.x + v.y + v.z + v.w;
    float ss = v.x*v.x + v.y*v.y + v.z*v.z + v.w*v.w;
    #pragma unroll
    for (int off = 32; off; off >>= 1) {
        s  += __shfl_down(s, off);
        ss += __shfl_down(ss, off);
    }
    __shared__ float rs[4], rss[4], stat[2];
    int wave = t >> 6, lane = t & 63;
    if (lane == 0) { rs[wave] = s; rss[wave] = ss; }
    __syncthreads();
    if (t == 0) {
        float a = rs[0] + rs[1] + rs[2] + rs[3];
        float b = rss[0] + rss[1] + rss[2] + rss[3];
        float mean = a * (1.0f / Ddim);
        float var  = b * (1.0f / Ddim) - mean * mean;
        stat[0] = mean;
        stat[1] = rsqrtf(var + 1e-5f);
    }
    __syncthreads();
    float mean = stat[0], inv = stat[1];
    float4 gv = ((const float4*)g)[t];
    float4 bv = ((const float4*)beta)[t];
    float4 o;
    o.x = (v.x - mean) * inv * gv.x + bv.x;
    o.y = (v.y - mean) * inv * gv.y + bv.y;
    o.z = (v.z - mean) * inv * gv.z + bv.z;
    o.w = (v.w - mean) * inv * gv.w + bv.w;
    if (SPLIT) {
        int d = t * 4;
        size_t off = ssa_off(row, d, Ddim);
        HL a0 = splitf(o.x), a1 = splitf(o.y), a2 = splitf(o.z), a3 = splitf(o.w);
        s16x4 hv, lv;
        hv[0] = a0.h; hv[1] = a1.h; hv[2] = a2.h; hv[3] = a3.h;
        lv[0] = a0.l; lv[1] = a1.l; lv[2] = a2.l; lv[3] = a3.l;
        *(s16x4*)&oh[off] = hv;
        *(s16x4*)&ol[off] = lv;
    } else {
        ((float4*)(outf + (size_t)row * Ddim))[t] = o;
    }
}

// ---------------------------------------------------------------------------
// Weight prepass (unchanged)
// ---------------------------------------------------------------------------
__global__ __launch_bounds__(256) void prep_w(
    const float* __restrict__ W, short* __restrict__ oh, short* __restrict__ ol,
    int N, int logN)
{
    int gi = blockIdx.x * 256 + threadIdx.x;
    int n = gi & (N - 1);
    int rest = gi >> logN;
    int g = rest & 7, kt = rest >> 3;
    const float* src = W + ((size_t)(kt * 64 + g * 8)) * N + n;
    s16x8 h8, l8;
    #pragma unroll
    for (int j = 0; j < 8; ++j) {
        HL a = splitf(src[(size_t)j * N]);
        h8[j] = a.h; l8[j] = a.l;
    }
    size_t off = ((size_t)kt * N + n) * 64 + (((g ^ (n & 7))) << 3);
    *(s16x8*)&oh[off] = h8;
    *(s16x8*)&ol[off] = l8;
}

// ---------------------------------------------------------------------------
// bf16x3 MFMA GEMM (R6-proven) + new VT epilogue for the V projection:
// V^T global layout per (b,h): [d 0..127][jtile 0..15][128B = 8 chunks of 8
// bf16; chunks 0-3 = hi of j-octets, 4-7 = lo; stored chunk = c ^ (d&7)].
// ---------------------------------------------------------------------------
struct G3 {
    const short* Wh[3]; const short* Wl[3];
    const float* bias[3];
    float* outf[3];
    short* oh[3]; short* ol[3];
    short* vt[3];
};

template<bool RES, bool RELU, bool SPLIT>
__global__ __launch_bounds__(256) void gemm3(
    const short* __restrict__ Ahi, const short* __restrict__ Alo,
    const float* __restrict__ res, G3 gp, int N, int K)
{
    __shared__ __align__(16) short As_h[128 * 64];
    __shared__ __align__(16) short As_l[128 * 64];
    __shared__ __align__(16) short Ws_h[64 * 64];
    __shared__ __align__(16) short Ws_l[64 * 64];

    int z = blockIdx.z;
    const short* Wh = gp.Wh[z];
    const short* Wl = gp.Wl[z];
    const float* bias = gp.bias[z];

    int t = threadIdx.x, wid = t >> 6, lane = t & 63;
    int bm = blockIdx.y * 128, bn = blockIdx.x * 64;
    int wr = wid >> 1, wc = wid & 1;

    f32x4 acc[4][2];
    #pragma unroll
    for (int m = 0; m < 4; ++m)
        #pragma unroll
        for (int n = 0; n < 2; ++n)
            acc[m][n] = (f32x4)(0.f);

    int nkt = K >> 6;
    int l8r = lane >> 3, l8c = lane & 7;

    for (int kt = 0; kt < nkt; ++kt) {
        size_t kof = (size_t)kt * 64 + l8c * 8;
        #pragma unroll
        for (int qq = 0; qq < 4; ++qq) {
            int rb = wid * 32 + qq * 8;
            gload16(Ahi + (size_t)(bm + rb + l8r) * K + kof, &As_h[rb * 64]);
            gload16(Alo + (size_t)(bm + rb + l8r) * K + kof, &As_l[rb * 64]);
        }
        size_t wbase = (size_t)kt * N * 64;
        #pragma unroll
        for (int qq = 0; qq < 2; ++qq) {
            int nb = wid * 16 + qq * 8;
            gload16(Wh + wbase + (size_t)(bn + nb + l8r) * 64 + l8c * 8, &Ws_h[nb * 64]);
            gload16(Wl + wbase + (size_t)(bn + nb + l8r) * 64 + l8c * 8, &Ws_l[nb * 64]);
        }
        __syncthreads();
        #pragma unroll
        for (int ks = 0; ks < 2; ++ks) {
            int kg = ks * 4 + (lane >> 4);
            int sw = (kg ^ (lane & 7)) << 3;
            bf16x8 ah[4], al[4], bh[2], bl[2];
            #pragma unroll
            for (int m = 0; m < 4; ++m) {
                int off = (wr * 64 + m * 16 + (lane & 15)) * 64 + sw;
                ah[m] = *(const bf16x8*)&As_h[off];
                al[m] = *(const bf16x8*)&As_l[off];
            }
            #pragma unroll
            for (int n = 0; n < 2; ++n) {
                int off = (wc * 32 + n * 16 + (lane & 15)) * 64 + sw;
                bh[n] = *(const bf16x8*)&Ws_h[off];
                bl[n] = *(const bf16x8*)&Ws_l[off];
            }
            #pragma unroll
            for (int m = 0; m < 4; ++m)
                #pragma unroll
                for (int n = 0; n < 2; ++n) {
                    acc[m][n] = __builtin_amdgcn_mfma_f32_16x16x32_bf16(ah[m], bh[n], acc[m][n], 0, 0, 0);
                    acc[m][n] = __builtin_amdgcn_mfma_f32_16x16x32_bf16(ah[m], bl[n], acc[m][n], 0, 0, 0);
                    acc[m][n] = __builtin_amdgcn_mfma_f32_16x16x32_bf16(al[m], bh[n], acc[m][n], 0, 0, 0);
                }
        }
        __syncthreads();
    }

    int r0 = (lane >> 4) << 2, cl = lane & 15;
    short* vtp = gp.vt[z];
    #pragma unroll
    for (int m = 0; m < 4; ++m) {
        #pragma unroll
        for (int n = 0; n < 2; ++n) {
            int col = bn + wc * 32 + n * 16 + cl;
            float bia = bias[col];
            #pragma unroll
            for (int j = 0; j < 4; ++j) {
                int row = bm + wr * 64 + m * 16 + r0 + j;
                float val = acc[m][n][j] + bia;
                if (RES) val += res[(size_t)row * N + col];
                if (RELU) val = fmaxf(val, 0.f);
                if (vtp) {
                    // V^T packed hi/lo swizzled layout
                    HL a = splitf(val);
                    int bb = row >> 9, jj2 = row & 511;
                    int hh = col >> 7, d = col & 127;
                    int bhI = bb * Hdim + hh;
                    int jt16 = jj2 >> 5;
                    int chi = (jj2 >> 3) & 3;
                    int ph = chi ^ (d & 7);
                    size_t base = (((size_t)bhI * 128 + d) * 16 + jt16) * 64;
                    vtp[base + ph * 8 + (jj2 & 7)] = a.h;
                    vtp[base + (ph ^ 4) * 8 + (jj2 & 7)] = a.l;
                } else if (SPLIT) {
                    HL a = splitf(val);
                    size_t o = ssa_off(row, col, N);
                    gp.oh[z][o] = a.h;
                    gp.ol[z][o] = a.l;
                } else {
                    gp.outf[z][(size_t)row * N + col] = val;
                }
            }
        }
    }
}

// ---------------------------------------------------------------------------
// qr[b,i,h,r] = q-row . rel_k[r,:]  (q now split-ssa bf16)
// ---------------------------------------------------------------------------
__global__ __launch_bounds__(256) void qr_kernel(
    const short* __restrict__ qh, const short* __restrict__ ql,
    const float* __restrict__ relk, float* __restrict__ qr)
{
    __shared__ __align__(16) float qrow[Ddim];
    __shared__ float rkT[DHdim][NRdim + 3];
    int bi = blockIdx.x, t = threadIdx.x;
    {
        int d0 = t * 4;
        int g = (d0 >> 3) & 7;
        int pos = g ^ (bi & 7);
        size_t off = (size_t)bi * Ddim + (d0 & ~63) + pos * 8 + (d0 & 7);
        s16x4 hv = *(const s16x4*)&qh[off];
        s16x4 lv = *(const s16x4*)&ql[off];
        #pragma unroll
        for (int e = 0; e < 4; ++e) qrow[d0 + e] = b2f(hv[e]) + b2f(lv[e]);
    }
    for (int idx = t; idx < NRdim * DHdim; idx += 256) {
        int r = idx >> 7, d = idx & 127;
        rkT[d][r] = relk[idx];
    }
    __syncthreads();
    for (int o = t; o < Hdim * NRdim; o += 256) {
        int h = o / NRdim, r = o - h * NRdim;
        const float* qp = qrow + h * DHdim;
        float acc = 0.f;
        #pragma unroll 4
        for (int d = 0; d < DHdim; ++d)
            acc = fmaf(qp[d], rkT[d][r], acc);
        qr[(size_t)bi * (Hdim * NRdim) + o] = acc;
    }
}

// ---------------------------------------------------------------------------
// MFMA attention. Block = (b,h, 32-q-row tile); 4 waves:
//   wid = kvhalf*2 + rowhalf: rows rowhalf*16.., kv range kvhalf*256..+256.
// Per wave per jt (KVBLK=32): swapped QK mfma(K, Qh/Ql) -> lane owns one
// q-row's 8 scores; online softmax (2 shfl_xor); P->bf16 cvt_pk + shfl-route;
// PV mfma(V^T hi/lo, P^T). KV-halves merged at end via LDS.
// ---------------------------------------------------------------------------
__global__ __launch_bounds__(256) void attn_mfma(
    const short* __restrict__ qh, const short* __restrict__ ql,
    const short* __restrict__ kh, const short* __restrict__ vt,
    const int* __restrict__ relations, const float* __restrict__ qr,
    const float* __restrict__ relv,
    short* __restrict__ o_hi, short* __restrict__ o_lo)
{
    __shared__ __align__(16) short Kh_s[2][32][128];   // 16 KB
    __shared__ __align__(16) short Vt_s[2][128][64];   // 32 KB (hi+lo packed)
    __shared__ float aw_s[4][16][NRdim + 3];           // 10.2 KB
    __shared__ float mg_s[2][16][2];

    int t = threadIdx.x;
    int wid = t >> 6, lane = t & 63;
    int q = lane & 15, g = lane >> 4;
    int rowhalf = wid & 1, kvhalf = wid >> 1;

    int blk = blockIdx.x;              // 512 = 16 itiles x (b*8+h)
    int it = blk & 15, bh = blk >> 4;
    int h = bh & 7, b = bh >> 3;
    int i0 = it * 32;
    int bL = b * Ldim;
    int rowg = bL + i0 + rowhalf * 16 + q;

    // zero aw
    for (int idx = t; idx < 4 * 16 * (NRdim + 3); idx += 256)
        ((float*)aw_s)[idx] = 0.f;

    // Q fragments in registers (B-operand): lane q-row, k-chunk g
    bf16x8 qhf[4], qlf[4];
    #pragma unroll
    for (int ks = 0; ks < 4; ++ks) {
        int c = (ks & 1) * 4 + g;
        size_t off = (size_t)rowg * Ddim + (h * 2 + (ks >> 1)) * 64
                   + ((c ^ (rowg & 7)) * 8);
        qhf[ks] = *(const bf16x8*)&qh[off];
        qlf[ks] = *(const bf16x8*)&ql[off];
    }

    const int*   relp = relations + (size_t)rowg * Ldim;
    const float* qrp  = qr + (size_t)rowg * (Hdim * NRdim) + h * NRdim;
    const float scale = 0.08838834764831845f;

    f32x4 acc_o[8];
    #pragma unroll
    for (int dt = 0; dt < 8; ++dt) acc_o[dt] = (f32x4)(0.f);
    float mrun = -1e30f, lsum = 0.f;
    float* awrow = &aw_s[wid][q][0];

    for (int rr = 0; rr < 8; ++rr) {
        // ---- cooperative staging of both streams (48 gload16 units) ----
        #pragma unroll
        for (int uu = 0; uu < 12; ++uu) {
            int u = wid * 12 + uu;
            if (u < 16) {
                int s = u >> 3, i = u & 7;
                const short* src = kh
                    + (size_t)(bL + s * 256 + rr * 32 + 4 * i + (lane >> 4)) * Ddim
                    + h * 128 + (lane & 15) * 8;
                gload16(src, &Kh_s[s][4 * i][0]);
            } else {
                int v = u - 16;
                int s = v >> 4, i = v & 15;
                const short* src = vt
                    + (((size_t)bh * 128 + 8 * i + (lane >> 3)) * 16 + s * 8 + rr) * 64
                    + (lane & 7) * 8;
                gload16(src, &Vt_s[s][8 * i][0]);
            }
        }
        __syncthreads();

        int st = kvhalf;
        int j0 = kvhalf * 256 + rr * 32;

        // ---- QK^T (swapped): lane -> q-row q, kcols Mt*16 + g*4 + jj ----
        f32x4 sAcc[2];
        sAcc[0] = (f32x4)(0.f); sAcc[1] = (f32x4)(0.f);
        #pragma unroll
        for (int Mt = 0; Mt < 2; ++Mt)
            #pragma unroll
            for (int ks = 0; ks < 4; ++ks) {
                int pos = (((ks & 1) * 4 + g) ^ (q & 7));
                bf16x8 kv = *(const bf16x8*)&Kh_s[st][Mt * 16 + q][(ks >> 1) * 64 + pos * 8];
                sAcc[Mt] = __builtin_amdgcn_mfma_f32_16x16x32_bf16(kv, qhf[ks], sAcc[Mt], 0, 0, 0);
                sAcc[Mt] = __builtin_amdgcn_mfma_f32_16x16x32_bf16(kv, qlf[ks], sAcc[Mt], 0, 0, 0);
            }

        // ---- scores + relation term ----
        float sv[8]; int r8[8];
        #pragma unroll
        for (int Mt = 0; Mt < 2; ++Mt)
            #pragma unroll
            for (int jj = 0; jj < 4; ++jj) {
                int kcol = Mt * 16 + g * 4 + jj;
                int rel = relp[j0 + kcol];
                r8[Mt * 4 + jj] = rel;
                sv[Mt * 4 + jj] = (sAcc[Mt][jj] + qrp[rel]) * scale;
            }

        // ---- online softmax (row group = lanes {q, q+16, q+32, q+48}) ----
        float mt = sv[0];
        #pragma unroll
        for (int k = 1; k < 8; ++k) mt = fmaxf(mt, sv[k]);
        mt = fmaxf(mt, __shfl_xor(mt, 16));
        mt = fmaxf(mt, __shfl_xor(mt, 32));
        float mnew = fmaxf(mrun, mt);
        float corr = __expf(mrun - mnew);
        mrun = mnew;
        float p[8]; float psum = 0.f;
        #pragma unroll
        for (int k = 0; k < 8; ++k) { p[k] = __expf(sv[k] - mnew); psum += p[k]; }
        lsum = lsum * corr + psum;
        #pragma unroll
        for (int dt = 0; dt < 8; ++dt) acc_o[dt] *= corr;
        // aw rescale (lane slots) then bucket adds — wave-lockstep safe
        int rbase = g * 10, nr = (g == 3) ? 7 : 10;
        for (int ri = 0; ri < nr; ++ri) awrow[rbase + ri] *= corr;
        #pragma unroll
        for (int k = 0; k < 8; ++k) atomicAdd(&awrow[r8[k]], p[k]);

        // ---- P -> bf16 pairs, route to B-frag layout ----
        u32 pk[4];
        asm("v_cvt_pk_bf16_f32 %0, %1, %2" : "=v"(pk[0]) : "v"(p[0]), "v"(p[1]));
        asm("v_cvt_pk_bf16_f32 %0, %1, %2" : "=v"(pk[1]) : "v"(p[2]), "v"(p[3]));
        asm("v_cvt_pk_bf16_f32 %0, %1, %2" : "=v"(pk[2]) : "v"(p[4]), "v"(p[5]));
        asm("v_cvt_pk_bf16_f32 %0, %1, %2" : "=v"(pk[3]) : "v"(p[6]), "v"(p[7]));
        union { u32 u[4]; bf16x8 v; } pb;
        int mtsel = g >> 1;
        #pragma unroll
        for (int i = 0; i < 4; ++i) {
            int src = q + 16 * ((2 * g + (i >> 1)) & 3);
            u32 lo = __shfl(pk[i & 1], src);
            u32 hi = __shfl(pk[2 + (i & 1)], src);
            pb.u[i] = mtsel ? hi : lo;
        }
        bf16x8 pfrag = pb.v;

        // ---- PV: acc_o[d-tile] += mfma(V^T, P^T) (hi + lo) ----
        #pragma unroll
        for (int dt = 0; dt < 8; ++dt) {
            int ph = g ^ (q & 7);
            bf16x8 vh = *(const bf16x8*)&Vt_s[st][dt * 16 + q][ph * 8];
            bf16x8 vl = *(const bf16x8*)&Vt_s[st][dt * 16 + q][(ph ^ 4) * 8];
            acc_o[dt] = __builtin_amdgcn_mfma_f32_16x16x32_bf16(vh, pfrag, acc_o[dt], 0, 0, 0);
            acc_o[dt] = __builtin_amdgcn_mfma_f32_16x16x32_bf16(vl, pfrag, acc_o[dt], 0, 0, 0);
        }
        __syncthreads();
    }

    // ---- finish: lsum reduce, o2 = aw @ rel_v ----
    lsum += __shfl_xor(lsum, 16);
    lsum += __shfl_xor(lsum, 32);
    for (int r = 0; r < NRdim; ++r) {
        float w = awrow[r];
        #pragma unroll
        for (int dt = 0; dt < 8; ++dt) {
            float4 rv = *(const float4*)&relv[r * DHdim + dt * 16 + g * 4];
            acc_o[dt][0] = fmaf(w, rv.x, acc_o[dt][0]);
            acc_o[dt][1] = fmaf(w, rv.y, acc_o[dt][1]);
            acc_o[dt][2] = fmaf(w, rv.z, acc_o[dt][2]);
            acc_o[dt][3] = fmaf(w, rv.w, acc_o[dt][3]);
        }
    }

    // ---- merge kv-halves (waves 2,3 publish; 0,1 merge + write) ----
    float* mrg = (float*)Vt_s;   // reuse (16 KB per rowhalf)
    if (kvhalf == 1) {
        float* mo = mrg + rowhalf * 2048;
        #pragma unroll
        for (int dt = 0; dt < 8; ++dt)
            #pragma unroll
            for (int jj = 0; jj < 4; ++jj)
                mo[q * 128 + dt * 16 + g * 4 + jj] = acc_o[dt][jj];
        if (g == 0) { mg_s[rowhalf][q][0] = mrun; mg_s[rowhalf][q][1] = lsum; }
    }
    __syncthreads();
    if (kvhalf == 0) {
        float m2 = mg_s[rowhalf][q][0], l2 = mg_s[rowhalf][q][1];
        float mf = fmaxf(mrun, m2);
        float a1 = __expf(mrun - mf), a2 = __expf(m2 - mf);
        float inv = 1.0f / (lsum * a1 + l2 * a2);
        float* mo = mrg + rowhalf * 2048;
        #pragma unroll
        for (int dt = 0; dt < 8; ++dt)
            #pragma unroll
            for (int jj = 0; jj < 4; ++jj) {
                int d = dt * 16 + g * 4 + jj;
                float O = acc_o[dt][jj] * a1 + mo[q * 128 + d] * a2;
                float out = O * inv;
                HL a = splitf(out);
                size_t off = ssa_off(rowg, h * DHdim + d, Ddim);
                o_hi[off] = a.h;
                o_lo[off] = a.l;
            }
    }
}

// ---------------------------------------------------------------------------
extern "C" void kernel_launch(void* const* d_in, const int* in_sizes, int n_in,
                              void* d_out, int out_size, void* d_ws, size_t ws_size,
                              hipStream_t stream)
{
    const float* x     = (const float*)d_in[0];
    const int*   rel   = (const int*)  d_in[1];
    const float* Wq    = (const float*)d_in[2];
    const float* bq    = (const float*)d_in[3];
    const float* Wk    = (const float*)d_in[4];
    const float* bk    = (const float*)d_in[5];
    const float* Wv    = (const float*)d_in[6];
    const float* bv    = (const float*)d_in[7];
    const float* Wo    = (const float*)d_in[8];
    const float* bo    = (const float*)d_in[9];
    const float* rel_k = (const float*)d_in[10];
    const float* rel_v = (const float*)d_in[11];
    const float* W1    = (const float*)d_in[12];
    const float* b1    = (const float*)d_in[13];
    const float* W2    = (const float*)d_in[14];
    const float* b2    = (const float*)d_in[15];
    const float* ln1_g = (const float*)d_in[16];
    const float* ln1_b = (const float*)d_in[17];
    const float* ln2_g = (const float*)d_in[18];
    const float* ln2_b = (const float*)d_in[19];
    const float* lnf_g = (const float*)d_in[20];
    const float* lnf_b = (const float*)d_in[21];

    const size_t MB = 1u << 20;
    char* w = (char*)d_ws;
    float* xbuf = (float*)w;                       // [0,8)
    short* h_hi = (short*)(w + 8 * MB);            // [8,12)
    short* h_lo = (short*)(w + 12 * MB);           // [12,16)
    short* qhB  = (short*)(w + 16 * MB);           // [16,20)
    short* qlB  = (short*)(w + 20 * MB);           // [20,24)
    short* khB  = (short*)(w + 24 * MB);           // [24,28)
    short* klB  = (short*)(w + 28 * MB);           // [28,32)
    short* vtB  = (short*)(w + 32 * MB);           // [32,40)
    float* qrb  = (float*)(w + 40 * MB);           // [40,42.4)
    short* o_hi = (short*)(w + 48 * MB);           // [48,52)
    short* o_lo = (short*)(w + 52 * MB);           // [52,56)
    short* wbh  = (short*)(w + 56 * MB);           // [56,64)
    short* wbl  = (short*)(w + 64 * MB);           // [64,72)
    short* ffh  = (short*)(w + 16 * MB);           // aliases q/k (dead in FFN)
    short* ffl  = (short*)(w + 32 * MB);           // aliases vt/qrb (dead in FFN)

    (void)hipMemcpyAsync(xbuf, x, sizeof(float) * (size_t)ROWS * Ddim,
                         hipMemcpyDeviceToDevice, stream);

    dim3 blk(256);
    const size_t MSH = 1048576;

    for (int l = 0; l < NLdim; ++l) {
        const float* Wq_l = Wq + (size_t)l * Ddim * Ddim;
        const float* Wk_l = Wk + (size_t)l * Ddim * Ddim;
        const float* Wv_l = Wv + (size_t)l * Ddim * Ddim;
        const float* Wo_l = Wo + (size_t)l * Ddim * Ddim;
        const float* W1_l = W1 + (size_t)l * Ddim * FFdim;
        const float* W2_l = W2 + (size_t)l * FFdim * Ddim;
        const float* rk_l = rel_k + (size_t)l * NRdim * DHdim;
        const float* rv_l = rel_v + (size_t)l * NRdim * DHdim;

        // --- attention sublayer ---
        ln_kernel<true><<<ROWS, blk, 0, stream>>>(xbuf, ln1_g + l * Ddim, ln1_b + l * Ddim,
                                                  nullptr, h_hi, h_lo);
        prep_w<<<512, blk, 0, stream>>>(Wq_l, wbh, wbl, Ddim, 10);
        prep_w<<<512, blk, 0, stream>>>(Wk_l, wbh + MSH, wbl + MSH, Ddim, 10);
        prep_w<<<512, blk, 0, stream>>>(Wv_l, wbh + 2 * MSH, wbl + 2 * MSH, Ddim, 10);
        {
            G3 g{};
            g.Wh[0] = wbh;           g.Wl[0] = wbl;
            g.Wh[1] = wbh + MSH;     g.Wl[1] = wbl + MSH;
            g.Wh[2] = wbh + 2 * MSH; g.Wl[2] = wbl + 2 * MSH;
            g.bias[0] = bq + l * Ddim; g.bias[1] = bk + l * Ddim; g.bias[2] = bv + l * Ddim;
            g.oh[0] = qhB; g.ol[0] = qlB;
            g.oh[1] = khB; g.ol[1] = klB;
            g.vt[2] = vtB;
            gemm3<false, false, true><<<dim3(16, 16, 3), blk, 0, stream>>>(
                h_hi, h_lo, nullptr, g, Ddim, Ddim);
        }
        qr_kernel<<<ROWS, blk, 0, stream>>>(qhB, qlB, rk_l, qrb);
        attn_mfma<<<512, blk, 0, stream>>>(qhB, qlB, khB, vtB, rel, qrb, rv_l, o_hi, o_lo);
        prep_w<<<512, blk, 0, stream>>>(Wo_l, wbh, wbl, Ddim, 10);
        {
            G3 g{};
            g.Wh[0] = wbh; g.Wl[0] = wbl;
            g.bias[0] = bo + l * Ddim;
            g.outf[0] = xbuf;
            gemm3<true, false, false><<<dim3(16, 16, 1), blk, 0, stream>>>(
                o_hi, o_lo, xbuf, g, Ddim, Ddim);
        }
        // --- FFN sublayer ---
        ln_kernel<true><<<ROWS, blk, 0, stream>>>(xbuf, ln2_g + l * Ddim, ln2_b + l * Ddim,
                                                  nullptr, h_hi, h_lo);
        prep_w<<<2048, blk, 0, stream>>>(W1_l, wbh, wbl, FFdim, 12);
        {
            G3 g{};
            g.Wh[0] = wbh; g.Wl[0] = wbl;
            g.bias[0] = b1 + l * FFdim;
            g.oh[0] = ffh; g.ol[0] = ffl;
            gemm3<false, true, true><<<dim3(64, 16, 1), blk, 0, stream>>>(
                h_hi, h_lo, nullptr, g, FFdim, Ddim);
        }
        prep_w<<<2048, blk, 0, stream>>>(W2_l, wbh, wbl, Ddim, 10);
        {
            G3 g{};
            g.Wh[0] = wbh; g.Wl[0] = wbl;
            g.bias[0] = b2 + l * Ddim;
            g.outf[0] = xbuf;
            gemm3<true, false, false><<<dim3(16, 16, 1), blk, 0, stream>>>(
                ffh, ffl, xbuf, g, Ddim, FFdim);
        }
    }
    ln_kernel<false><<<ROWS, blk, 0, stream>>>(xbuf, lnf_g, lnf_b, (float*)d_out,
                                               nullptr, nullptr);
}